// Round 1
// baseline (5454.436 us; speedup 1.0000x reference)
//
#include <hip/hip_runtime.h>
#include <math.h>

// DIN fused kernel. B=4096, S=200, E=64, H=128.
// Key identity: att_in @ att_w1 = beh @ (W1a+W1c+diag(t)W1d) + t @ (W1b-W1c)
// -> per-b effective 64x128 weight (held in registers, column per thread).

#define S_LEN 200
#define S_PAD 208   // 13 chunks of 16

__device__ __forceinline__ float waveReduceSum(float v) {
#pragma unroll
  for (int m = 32; m; m >>= 1) v += __shfl_xor(v, m, 64);
  return v;
}

__device__ __forceinline__ void async_g2l_16(const float* g, float* l) {
  __builtin_amdgcn_global_load_lds(
      (const __attribute__((address_space(1))) void*)g,
      (__attribute__((address_space(3))) void*)l, 16, 0, 0);
}

__global__ __launch_bounds__(256, 2)
void din_fused(const int* __restrict__ uf, const int* __restrict__ tif,
               const int* __restrict__ bseq,
               const float* __restrict__ e0, const float* __restrict__ e1,
               const float* __restrict__ ei,
               const float* __restrict__ aw1, const float* __restrict__ ab1,
               const float* __restrict__ aw2, const float* __restrict__ ab2,
               const float* __restrict__ fw1, const float* __restrict__ fb1,
               const float* __restrict__ fw2, const float* __restrict__ fb2,
               float* __restrict__ out)
{
  __shared__ float sBeh[S_PAD * 64];   // 53248 B, rows 200..207 zeroed
  __shared__ float sScores[S_PAD];
  __shared__ float sRed[64];
  __shared__ float sPart[256];
  __shared__ float sComb[256];

  const int b    = blockIdx.x;
  const int tid  = threadIdx.x;
  const int lane = tid & 63;
  const int wv   = tid >> 6;

  const int ti = tif[b];
  const long tbase = (long)ti * 64;

  // ---- Phase 0: gather behavior rows directly into LDS (async) ----
  // iteration it covers rows it*16 .. it*16+15; thread -> row=it*16+tid/16, col=(tid&15)*4
  // LDS float offset = row*64 + col = it*1024 + tid*4  (linear in tid -> global_load_lds ok)
#pragma unroll
  for (int it = 0; it < 13; ++it) {
    const int row = it * 16 + (tid >> 4);
    if (row < S_LEN) {
      const int idx = bseq[b * S_LEN + row];
      const float* src = ei + (long)idx * 64 + (tid & 15) * 4;
      async_g2l_16(src, &sBeh[it * 1024 + wv * 256]);
    } else {
      // rows 200..207 -> zeros (only it==12, waves 2,3)
      float4 z = {0.f, 0.f, 0.f, 0.f};
      *(float4*)&sBeh[it * 1024 + tid * 4] = z;
    }
  }

  // ---- Phase 1: build W_eff column (h = tid&127) in registers + bias c[h] ----
  const int h  = tid & 127;
  const int sl = tid >> 7;   // which s-octet this thread serves per chunk
  float4 wf[16];
  float cH = ab1[h];
#pragma unroll
  for (int d4 = 0; d4 < 16; ++d4) {
    const float4 t4 = ((const float4*)(ei + tbase))[d4];  // broadcast target row
    const float tt[4] = {t4.x, t4.y, t4.z, t4.w};
    float wtmp[4];
#pragma unroll
    for (int j = 0; j < 4; ++j) {
      const int d = d4 * 4 + j;
      const float a  = aw1[(d)       * 128 + h];
      const float bm = aw1[(64 + d)  * 128 + h];
      const float cm = aw1[(128 + d) * 128 + h];
      const float dm = aw1[(192 + d) * 128 + h];
      wtmp[j] = a + cm + tt[j] * dm;
      cH = fmaf(tt[j], bm - cm, cH);
    }
    wf[d4] = make_float4(wtmp[0], wtmp[1], wtmp[2], wtmp[3]);
  }
  const float w2h = aw2[h];
  const float b2v = ab2[0];

  __syncthreads();  // gathers drained (vmcnt0 at barrier), sBeh ready

  // ---- Phase 2: scores. chunk = 16 s; thread does 8 s for its h column ----
#pragma unroll 1
  for (int ch = 0; ch < 13; ++ch) {
    const int s0 = ch * 16 + sl * 8;
    float acc[8];
#pragma unroll
    for (int k = 0; k < 8; ++k) acc[k] = cH;
#pragma unroll
    for (int d4 = 0; d4 < 16; ++d4) {
      const float4 w = wf[d4];
#pragma unroll
      for (int k = 0; k < 8; ++k) {
        const float4 bb = *(const float4*)&sBeh[(s0 + k) * 64 + d4 * 4];  // wave-uniform: broadcast
        acc[k] = fmaf(bb.x, w.x, acc[k]);
        acc[k] = fmaf(bb.y, w.y, acc[k]);
        acc[k] = fmaf(bb.z, w.z, acc[k]);
        acc[k] = fmaf(bb.w, w.w, acc[k]);
      }
    }
#pragma unroll
    for (int k = 0; k < 8; ++k) {
      float v = fmaxf(acc[k], 0.f) * w2h;
      v = waveReduceSum(v);
      if (lane == 0) sRed[wv * 8 + k] = v;
    }
    __syncthreads();
    if (tid < 16) {
      const int k = tid & 7, g = tid >> 3;
      const int s = ch * 16 + g * 8 + k;
      // s-octet g is served by waves {2g, 2g+1} (low/high h halves)
      if (s < S_LEN) sScores[s] = sRed[(g * 2) * 8 + k] + sRed[(g * 2 + 1) * 8 + k] + b2v;
    }
    __syncthreads();
  }

  // ---- Phase 3: softmax over 200 scores ----
  if (tid < 64) {
    float m = -1e30f;
    for (int i = tid; i < S_LEN; i += 64) m = fmaxf(m, sScores[i]);
#pragma unroll
    for (int mm = 32; mm; mm >>= 1) m = fmaxf(m, __shfl_xor(m, mm, 64));
    if (tid == 0) sRed[0] = m;
  }
  __syncthreads();
  const float M = sRed[0];
  if (tid < 64) {
    float ss = 0.f;
    for (int i = tid; i < S_LEN; i += 64) {
      float e = expf(sScores[i] - M);
      sScores[i] = e;
      ss += e;
    }
    ss = waveReduceSum(ss);
    if (tid == 0) sRed[1] = ss;
  }
  __syncthreads();
  const float invSum = 1.f / sRed[1];

  // ---- Phase 4: user_interest[e] = sum_s w[s]*beh[s][e]; stage combined ----
  {
    const int g = tid >> 6, e = lane;
    float a = 0.f;
    for (int s = g; s < S_LEN; s += 4) a = fmaf(sScores[s], sBeh[s * 64 + e], a);
    sPart[g * 64 + e] = a;
  }
  const int u0 = uf[b * 2 + 0];
  const int u1 = uf[b * 2 + 1];
  if (tid < 64)       sComb[tid] = e0[(long)u0 * 64 + tid];
  else if (tid < 128) sComb[tid] = e1[(long)u1 * 64 + (tid - 64)];
  else if (tid >= 192) sComb[tid] = ei[tbase + (tid - 192)];
  __syncthreads();
  if (tid < 64)
    sComb[128 + tid] = (sPart[tid] + sPart[64 + tid] + sPart[128 + tid] + sPart[192 + tid]) * invSum;
  __syncthreads();

  // ---- Phase 5: FC head: relu(comb @ fw1 + fb1) @ fw2 + fb2 ----
  {
    const int j = tid & 127, half = tid >> 7;
    float a = 0.f;
#pragma unroll 8
    for (int dd = 0; dd < 128; ++dd) {
      const int d = half * 128 + dd;
      a = fmaf(sComb[d], fw1[d * 128 + j], a);
    }
    sPart[half * 128 + j] = a;
  }
  __syncthreads();
  if (tid < 128) {
    float tot = sPart[tid] + sPart[128 + tid] + fb1[tid];
    float v = fmaxf(tot, 0.f) * fw2[tid];
    v = waveReduceSum(v);
    if (lane == 0) sRed[8 + (tid >> 6)] = v;
  }
  __syncthreads();
  if (tid == 0) out[b] = sRed[8] + sRed[9] + fb2[0];
}

extern "C" void kernel_launch(void* const* d_in, const int* in_sizes, int n_in,
                              void* d_out, int out_size, void* d_ws, size_t ws_size,
                              hipStream_t stream) {
  const int*   uf   = (const int*)d_in[0];
  const int*   tif  = (const int*)d_in[1];
  const int*   bseq = (const int*)d_in[2];
  const float* e0   = (const float*)d_in[3];
  const float* e1   = (const float*)d_in[4];
  const float* ei   = (const float*)d_in[5];
  const float* aw1  = (const float*)d_in[6];
  const float* ab1  = (const float*)d_in[7];
  const float* aw2  = (const float*)d_in[8];
  const float* ab2  = (const float*)d_in[9];
  const float* fw1  = (const float*)d_in[10];
  const float* fb1  = (const float*)d_in[11];
  const float* fw2  = (const float*)d_in[12];
  const float* fb2  = (const float*)d_in[13];
  float* o = (float*)d_out;

  din_fused<<<dim3(4096), dim3(256), 0, stream>>>(
      uf, tif, bseq, e0, e1, ei, aw1, ab1, aw2, ab2, fw1, fb1, fw2, fb2, o);
}

// Round 2
// 158.220 us; speedup vs baseline: 34.4737x; 34.4737x over previous
//
#include <hip/hip_runtime.h>
#include <math.h>

// DIN fused, round 2: MFMA score GEMM + no big register arrays.
// Identity: att_in @ att_w1 = beh @ W_eff + cH, W_eff = W1a+W1c+diag(t)W1d,
// cH = t@(W1b-W1c) + b1. W_eff lives in LDS (bf16, swizzled), scores via
// v_mfma_f32_16x16x32_bf16.

#define S_LEN 200
#define S_PAD 208

typedef __attribute__((ext_vector_type(8))) short short8;
typedef __attribute__((ext_vector_type(4))) float f32x4;

__device__ __forceinline__ float waveReduceSum(float v) {
#pragma unroll
  for (int m = 32; m; m >>= 1) v += __shfl_xor(v, m, 64);
  return v;
}

__device__ __forceinline__ unsigned short f2b(float f) {
  union { float f; unsigned u; } x; x.f = f;
  unsigned r = x.u + 0x7fffu + ((x.u >> 16) & 1u);  // RNE
  return (unsigned short)(r >> 16);
}
__device__ __forceinline__ float b2f(unsigned short h) {
  union { unsigned u; float f; } x; x.u = ((unsigned)h) << 16; return x.f;
}

// swizzled ushort-index into a [row][64] bf16 tile (row stride 128 B).
// XOR row&7 into byte bits 4..6 -> conflict-free ds_read_b128 down a column.
__device__ __forceinline__ int swz(int row, int col) {
  int byte = row * 128 + col * 2;
  byte ^= (row & 7) << 4;
  return byte >> 1;
}

__global__ __launch_bounds__(256, 4)
void din_fused(const int* __restrict__ uf, const int* __restrict__ tif,
               const int* __restrict__ bseq,
               const float* __restrict__ e0, const float* __restrict__ e1,
               const float* __restrict__ ei,
               const float* __restrict__ aw1, const float* __restrict__ ab1,
               const float* __restrict__ aw2, const float* __restrict__ ab2,
               const float* __restrict__ fw1, const float* __restrict__ fb1,
               const float* __restrict__ fw2, const float* __restrict__ fb2,
               float* __restrict__ out)
{
  __shared__ unsigned short sBehB[S_PAD * 64];  // bf16, swizzled   26624 B
  __shared__ unsigned short sW[128 * 64];       // W_eff^T [h][d]   16384 B
  __shared__ float sCH[256];                    // cH partials
  __shared__ float sPartS[4 * S_PAD];           // per-wave score partials / scratch
  __shared__ float sScores[S_PAD];
  __shared__ float sRed[16];
  __shared__ float sComb[256];

  const int b    = blockIdx.x;
  const int tid  = threadIdx.x;
  const int lane = tid & 63;
  const int wv   = tid >> 6;

  const int ti = tif[b];
  const size_t tbase = (size_t)ti * 64;

  // ---- Phase 0: gather behavior rows -> bf16 LDS (reg-staged, swizzled) ----
  // 16 threads per row, 4 floats each.
#pragma unroll
  for (int it = 0; it < 13; ++it) {
    const int row = it * 16 + (tid >> 4);
    float4 v = make_float4(0.f, 0.f, 0.f, 0.f);
    if (row < S_LEN) {
      const int idx = bseq[b * S_LEN + row];
      v = *(const float4*)(ei + (size_t)idx * 64 + (tid & 15) * 4);
    }
    ushort4 pk;
    pk.x = f2b(v.x); pk.y = f2b(v.y); pk.z = f2b(v.z); pk.w = f2b(v.w);
    *(ushort4*)&sBehB[swz(row, (tid & 15) * 4)] = pk;
  }

  // ---- Phase 1: W_eff^T -> sW (bf16, swizzled), cH partials -> sCH ----
  {
    const int h = tid & 127, dh = tid >> 7;
    float cpart = 0.f;
#pragma unroll
    for (int dp = 0; dp < 16; ++dp) {
      const int d = dh * 32 + dp * 2;
      const float t0 = ei[tbase + d], t1 = ei[tbase + d + 1];
      const float wa0 = aw1[(d)       * 128 + h];
      const float wb0 = aw1[(64 + d)  * 128 + h];
      const float wc0 = aw1[(128 + d) * 128 + h];
      const float wd0 = aw1[(192 + d) * 128 + h];
      const float wa1 = aw1[(d + 1)     * 128 + h];
      const float wb1 = aw1[(65 + d)    * 128 + h];
      const float wc1 = aw1[(129 + d)   * 128 + h];
      const float wd1 = aw1[(193 + d)   * 128 + h];
      const float w0 = wa0 + wc0 + t0 * wd0;
      const float w1 = wa1 + wc1 + t1 * wd1;
      cpart += t0 * (wb0 - wc0) + t1 * (wb1 - wc1);
      const unsigned pk = (unsigned)f2b(w0) | ((unsigned)f2b(w1) << 16);
      *(unsigned*)&sW[swz(h, d)] = pk;
    }
    sCH[dh * 128 + h] = cpart;
  }

  __syncthreads();

  // ---- Phase 2: scores via MFMA. Wave wv owns h-cols [wv*32, wv*32+32) ----
  {
    const int hl = lane & 15, rq = lane >> 4;
    const int h0 = wv * 32 + hl, h1 = h0 + 16;
    const float cH0 = sCH[h0] + sCH[128 + h0] + ab1[h0];
    const float cH1 = sCH[h1] + sCH[128 + h1] + ab1[h1];
    const float w20 = aw2[h0], w21 = aw2[h1];

#pragma unroll 1
    for (int mt = 0; mt < 13; ++mt) {
      f32x4 acc0 = {0.f, 0.f, 0.f, 0.f};
      f32x4 acc1 = {0.f, 0.f, 0.f, 0.f};
#pragma unroll
      for (int kk = 0; kk < 2; ++kk) {
        const short8 av = *(const short8*)&sBehB[swz(mt * 16 + hl, kk * 32 + rq * 8)];
        const short8 b0 = *(const short8*)&sW[swz(h0, kk * 32 + rq * 8)];
        const short8 b1 = *(const short8*)&sW[swz(h1, kk * 32 + rq * 8)];
        acc0 = __builtin_amdgcn_mfma_f32_16x16x32_bf16(av, b0, acc0, 0, 0, 0);
        acc1 = __builtin_amdgcn_mfma_f32_16x16x32_bf16(av, b1, acc1, 0, 0, 0);
      }
      // epilogue: relu(+bias)*w2, reduce over this wave's 32 h-cols
#pragma unroll
      for (int r = 0; r < 4; ++r) {
        float v = fmaxf(acc0[r] + cH0, 0.f) * w20 + fmaxf(acc1[r] + cH1, 0.f) * w21;
        v += __shfl_xor(v, 1, 64);
        v += __shfl_xor(v, 2, 64);
        v += __shfl_xor(v, 4, 64);
        v += __shfl_xor(v, 8, 64);
        if (hl == 0) sPartS[wv * S_PAD + mt * 16 + rq * 4 + r] = v;
      }
    }
  }
  __syncthreads();

  // ---- Phase 3: combine partials, softmax over 200 ----
  if (tid < S_LEN) {
    sScores[tid] = sPartS[tid] + sPartS[S_PAD + tid] + sPartS[2 * S_PAD + tid]
                 + sPartS[3 * S_PAD + tid] + ab2[0];
  }
  __syncthreads();

  if (tid < 64) {
    float m = -1e30f;
    for (int i = tid; i < S_LEN; i += 64) m = fmaxf(m, sScores[i]);
#pragma unroll
    for (int mm = 32; mm; mm >>= 1) m = fmaxf(m, __shfl_xor(m, mm, 64));
    if (tid == 0) sRed[0] = m;
  }
  __syncthreads();
  const float M = sRed[0];
  if (tid < 64) {
    float ss = 0.f;
    for (int i = tid; i < S_LEN; i += 64) {
      const float e = expf(sScores[i] - M);
      sScores[i] = e;
      ss += e;
    }
    ss = waveReduceSum(ss);
    if (tid == 0) sRed[1] = ss;
  }
  __syncthreads();

  // ---- Phase 4: pooling + stage combined vector ----
  {
    float a = 0.f;
    for (int s = wv; s < S_LEN; s += 4)
      a = fmaf(sScores[s], b2f(sBehB[swz(s, lane)]), a);
    sPartS[wv * 64 + lane] = a;
  }
  const int u0 = uf[b * 2 + 0];
  const int u1 = uf[b * 2 + 1];
  if (tid < 64)       sComb[tid] = e0[(size_t)u0 * 64 + tid];
  else if (tid < 128) sComb[tid] = e1[(size_t)u1 * 64 + (tid - 64)];
  else if (tid >= 192) sComb[tid] = ei[tbase + (tid - 192)];
  __syncthreads();
  const float invSum = 1.f / sRed[1];
  if (tid < 64)
    sComb[128 + tid] = (sPartS[tid] + sPartS[64 + tid] + sPartS[128 + tid]
                      + sPartS[192 + tid]) * invSum;
  __syncthreads();

  // ---- Phase 5: FC head (f32) ----
  {
    const int j = tid & 127, half = tid >> 7;
    float a = 0.f;
#pragma unroll 8
    for (int dd = 0; dd < 128; ++dd) {
      const int d = half * 128 + dd;
      a = fmaf(sComb[d], fw1[d * 128 + j], a);
    }
    sPartS[half * 128 + j] = a;
  }
  __syncthreads();
  if (tid < 128) {
    const float tot = sPartS[tid] + sPartS[128 + tid] + fb1[tid];
    float v = fmaxf(tot, 0.f) * fw2[tid];
    v = waveReduceSum(v);
    if (lane == 0) sRed[8 + (tid >> 6)] = v;
  }
  __syncthreads();
  if (tid == 0) out[b] = sRed[8] + sRed[9] + fb2[0];
}

extern "C" void kernel_launch(void* const* d_in, const int* in_sizes, int n_in,
                              void* d_out, int out_size, void* d_ws, size_t ws_size,
                              hipStream_t stream) {
  const int*   uf   = (const int*)d_in[0];
  const int*   tif  = (const int*)d_in[1];
  const int*   bseq = (const int*)d_in[2];
  const float* e0   = (const float*)d_in[3];
  const float* e1   = (const float*)d_in[4];
  const float* ei   = (const float*)d_in[5];
  const float* aw1  = (const float*)d_in[6];
  const float* ab1  = (const float*)d_in[7];
  const float* aw2  = (const float*)d_in[8];
  const float* ab2  = (const float*)d_in[9];
  const float* fw1  = (const float*)d_in[10];
  const float* fb1  = (const float*)d_in[11];
  const float* fw2  = (const float*)d_in[12];
  const float* fb2  = (const float*)d_in[13];
  float* o = (float*)d_out;

  din_fused<<<dim3(4096), dim3(256), 0, stream>>>(
      uf, tif, bseq, e0, e1, ei, aw1, ab1, aw2, ab2, fw1, fb1, fw2, fb2, o);
}

// Round 3
// 133.314 us; speedup vs baseline: 40.9141x; 1.1868x over previous
//
#include <hip/hip_runtime.h>
#include <math.h>

// DIN fused, round 3. Three kernels:
//  k0 prep: A'=W1a+W1c, D'=W1d as [h][d] bf16; Bm=W1b-W1c as [d][h] bf16;
//           fw1^T pre-swizzled bf16 image (for k2 global_load_lds).
//  k1 main: 8 b's/block. Score GEMM h = beh@(A'+diag(t)D') + t@Bm + b1 via
//           mfma_16x16x32_bf16, B-fragments in registers (block-invariant A',D').
//           softmax + pooling; writes combined[4096][256] f32 to ws.
//  k2 FC:   relu(comb@fw1+b1)@fw2+b2 via MFMA, 16 b's/block.

#define S_LEN 200
#define S_PAD 208

typedef __attribute__((ext_vector_type(8))) short short8;
typedef __attribute__((ext_vector_type(4))) float f32x4;

__device__ __forceinline__ unsigned short f2b(float f) {
  union { float f; unsigned u; } x; x.f = f;
  unsigned r = x.u + 0x7fffu + ((x.u >> 16) & 1u);
  return (unsigned short)(r >> 16);
}
__device__ __forceinline__ float b2f(unsigned short h) {
  union { unsigned u; float f; } x; x.u = ((unsigned)h) << 16; return x.f;
}

// [row][64] bf16 tile, row stride 128 B -> ushort index
__device__ __forceinline__ int swzB(int row, int col) {
  int byte = row * 128 + col * 2;
  byte ^= (row & 7) << 4;
  return byte >> 1;
}
// [row][256] bf16 tile, row stride 512 B -> ushort index
__device__ __forceinline__ int swzW(int row, int col) {
  int byte = row * 512 + col * 2;
  byte ^= (row & 7) << 4;
  return byte >> 1;
}

__device__ __forceinline__ void async_g2l_16(const void* g, void* l) {
  __builtin_amdgcn_global_load_lds(
      (const __attribute__((address_space(1))) void*)g,
      (__attribute__((address_space(3))) void*)l, 16, 0, 0);
}

// ---------------- workspace layout (bytes) ----------------
// comb  f32 [4096][256] : 0        .. 4194304
// A'T   bf16 [128][64]  : 4194304  .. +16384
// D'T   bf16 [128][64]  : 4210688  .. +16384
// Bm    bf16 [64][128]  : 4227072  .. +16384
// fw1T  bf16 swz image  : 4243456  .. +65536
#define WS_COMB 0
#define WS_AT   4194304
#define WS_DT   4210688
#define WS_BM   4227072
#define WS_FW1T 4243456

// ================= k0: prep =================
__global__ __launch_bounds__(256)
void din_prep(const float* __restrict__ aw1, const float* __restrict__ fw1,
              char* __restrict__ ws)
{
  unsigned short* AT   = (unsigned short*)(ws + WS_AT);
  unsigned short* DT   = (unsigned short*)(ws + WS_DT);
  unsigned short* Bm   = (unsigned short*)(ws + WS_BM);
  unsigned short* FW1T = (unsigned short*)(ws + WS_FW1T);
  const int blk = blockIdx.x, tid = threadIdx.x;

  if (blk < 32) {               // A'T, D'T : [h][d]
    const int i = blk * 256 + tid;      // 0..8191
    const int h = i >> 6, d = i & 63;
    const float a = aw1[d * 128 + h];
    const float c = aw1[(128 + d) * 128 + h];
    const float dd = aw1[(192 + d) * 128 + h];
    AT[i] = f2b(a + c);
    DT[i] = f2b(dd);
  } else if (blk < 64) {        // Bm : [d][h]
    const int j = (blk - 32) * 256 + tid;  // 0..8191
    const int d = j >> 7, h = j & 127;
    Bm[j] = f2b(aw1[(64 + d) * 128 + h] - aw1[(128 + d) * 128 + h]);
  } else {                      // fw1T swizzled image
    const int i = (blk - 64) * 256 + tid;  // 0..32767
    const int o = 2 * i;
    const int h = o >> 9;
    const int rr = o & 511;
    const int d = (rr ^ ((h & 7) << 4)) >> 1;
    FW1T[i] = f2b(fw1[d * 128 + h]);
  }
}

// ================= k1: main =================
__global__ __launch_bounds__(512, 4)
void din_main(const int* __restrict__ uf, const int* __restrict__ tif,
              const int* __restrict__ bseq,
              const float* __restrict__ e0, const float* __restrict__ e1,
              const float* __restrict__ ei,
              const float* __restrict__ ab1, const float* __restrict__ aw2,
              char* __restrict__ ws)
{
  __shared__ unsigned short sBehB[S_PAD * 64];  // 26624 B (aliased as Bm stage)
  __shared__ int   sIdx[1600];                  // 6400
  __shared__ float sT[8 * 64];                  // 2048
  __shared__ float sCH[8 * 128];                // 4096
  __shared__ float sPart[8 * S_PAD];            // 6656
  __shared__ float sScores[S_PAD];              // 832
  __shared__ float sPool[8 * 64];               // 2048
  __shared__ float sRedM[8], sRedS[8];

  float* comb = (float*)(ws + WS_COMB);
  const unsigned short* ATws = (const unsigned short*)(ws + WS_AT);
  const unsigned short* DTws = (const unsigned short*)(ws + WS_DT);

  const int tid  = threadIdx.x;
  const int lane = tid & 63;
  const int wv   = tid >> 6;
  const int bb   = blockIdx.x * 8;

  // ---- block prologue ----
  for (int k = tid; k < 1600; k += 512) sIdx[k] = bseq[bb * 200 + k];
  {
    const int g = tid >> 6, d = tid & 63;
    const int b = bb + g;
    const int u0 = uf[2 * b], u1 = uf[2 * b + 1], ti = tif[b];
    const float tv = ei[(size_t)ti * 64 + d];
    sT[g * 64 + d] = tv;
    float* cb = comb + (size_t)b * 256;
    cb[192 + d] = tv;
    cb[d]       = e0[(size_t)u0 * 64 + d];
    cb[64 + d]  = e1[(size_t)u1 * 64 + d];
  }
  // stage Bm (plain [d][h] bf16, 16 KB) into sBehB region
  {
    char* dst = (char*)sBehB;
    const char* src = ws + WS_BM;
#pragma unroll
    for (int it = 0; it < 2; ++it)
      async_g2l_16(src + it * 8192 + tid * 16, dst + it * 8192 + tid * 16);
  }
  // hoist per-lane B-fragment sources (block-invariant)
  const int hl = lane & 15, rq = lane >> 4;
  const int h  = wv * 16 + hl;
  short8 aT[2], dT[2];
#pragma unroll
  for (int kk = 0; kk < 2; ++kk) {
    aT[kk] = *(const short8*)(ATws + h * 64 + kk * 32 + rq * 8);
    dT[kk] = *(const short8*)(DTws + h * 64 + kk * 32 + rq * 8);
  }
  const float w2h = aw2[h];
  const float abv = ab1[h];

  __syncthreads();  // sBm staged (vmcnt drained), sT/sIdx ready

  // ---- cH[b][h] = t[b] . Bm[:,h] ----
  {
    const unsigned short* sBm = sBehB;
    const int h2 = tid & 127, bq = tid >> 7;  // bq in 0..3 -> b pair {2bq, 2bq+1}
    float c0 = 0.f, c1 = 0.f;
    const float* t0 = sT + (2 * bq) * 64;
    const float* t1 = sT + (2 * bq + 1) * 64;
#pragma unroll 8
    for (int d = 0; d < 64; ++d) {
      const float bmv = b2f(sBm[d * 128 + h2]);
      c0 = fmaf(t0[d], bmv, c0);
      c1 = fmaf(t1[d], bmv, c1);
    }
    sCH[(2 * bq) * 128 + h2] = c0;
    sCH[(2 * bq + 1) * 128 + h2] = c1;
  }
  __syncthreads();  // cH ready; sBm region now reusable as sBehB

  // ---- per-b loop ----
  for (int g = 0; g < 8; ++g) {
    const int b = bb + g;

    // gather 200 rows -> registers
    float4 gv[7];
#pragma unroll
    for (int it = 0; it < 7; ++it) {
      const int row = it * 32 + (tid >> 4);
      if (row < S_LEN) {
        const int idx = sIdx[g * 200 + row];
        gv[it] = *(const float4*)(ei + (size_t)idx * 64 + (tid & 15) * 4);
      }
    }

    // per-b B-fragments: w[kk] = aT + t (.) dT   (bf16)
    short8 w[2];
    const float cHh = sCH[g * 128 + h] + abv;
    {
      const float* tb = sT + g * 64;
#pragma unroll
      for (int kk = 0; kk < 2; ++kk) {
        const float4 ta = *(const float4*)(tb + kk * 32 + rq * 8);
        const float4 tc = *(const float4*)(tb + kk * 32 + rq * 8 + 4);
        const float tt[8] = {ta.x, ta.y, ta.z, ta.w, tc.x, tc.y, tc.z, tc.w};
        union { short8 s; unsigned u[4]; } out;
#pragma unroll
        for (int p = 0; p < 4; ++p) {
          const float lo = fmaf(tt[2 * p],     b2f((unsigned short)dT[kk][2 * p]),     b2f((unsigned short)aT[kk][2 * p]));
          const float hi = fmaf(tt[2 * p + 1], b2f((unsigned short)dT[kk][2 * p + 1]), b2f((unsigned short)aT[kk][2 * p + 1]));
          out.u[p] = (unsigned)f2b(lo) | ((unsigned)f2b(hi) << 16);
        }
        w[kk] = out.s;
      }
    }

    // stash gathered rows -> swizzled bf16 LDS
#pragma unroll
    for (int it = 0; it < 7; ++it) {
      const int row = it * 32 + (tid >> 4);
      if (row < S_LEN) {
        ushort4 pk;
        pk.x = f2b(gv[it].x); pk.y = f2b(gv[it].y);
        pk.z = f2b(gv[it].z); pk.w = f2b(gv[it].w);
        *(ushort4*)&sBehB[swzB(row, (tid & 15) * 4)] = pk;
      } else if (row < S_PAD) {
        ushort4 z = {0, 0, 0, 0};
        *(ushort4*)&sBehB[swzB(row, (tid & 15) * 4)] = z;
      }
    }
    __syncthreads();  // (1) sBehB ready

    // scores: wave wv owns h-cols [wv*16, wv*16+16)
#pragma unroll 1
    for (int mt = 0; mt < 13; ++mt) {
      f32x4 acc = {0.f, 0.f, 0.f, 0.f};
#pragma unroll
      for (int kk = 0; kk < 2; ++kk) {
        const short8 av = *(const short8*)&sBehB[swzB(mt * 16 + hl, kk * 32 + rq * 8)];
        acc = __builtin_amdgcn_mfma_f32_16x16x32_bf16(av, w[kk], acc, 0, 0, 0);
      }
#pragma unroll
      for (int r = 0; r < 4; ++r) {
        float v = fmaxf(acc[r] + cHh, 0.f) * w2h;
        v += __shfl_xor(v, 1, 64);
        v += __shfl_xor(v, 2, 64);
        v += __shfl_xor(v, 4, 64);
        v += __shfl_xor(v, 8, 64);
        if (hl == 0) sPart[wv * S_PAD + mt * 16 + rq * 4 + r] = v;
      }
    }
    __syncthreads();  // (2) sPart ready

    // combine + softmax max
    float sc = -1e30f;
    if (tid < S_LEN) {
      float a0 = sPart[tid]             + sPart[S_PAD + tid];
      float a1 = sPart[2 * S_PAD + tid] + sPart[3 * S_PAD + tid];
      float a2 = sPart[4 * S_PAD + tid] + sPart[5 * S_PAD + tid];
      float a3 = sPart[6 * S_PAD + tid] + sPart[7 * S_PAD + tid];
      sc = (a0 + a1) + (a2 + a3);
    }
    {
      float m = sc;
#pragma unroll
      for (int mm = 32; mm; mm >>= 1) m = fmaxf(m, __shfl_xor(m, mm, 64));
      if (lane == 0) sRedM[wv] = m;
    }
    __syncthreads();  // (3) maxes
    float M = sRedM[0];
#pragma unroll
    for (int i = 1; i < 8; ++i) M = fmaxf(M, sRedM[i]);
    float e = 0.f;
    if (tid < S_LEN) {
      e = __expf(sc - M);
      sScores[tid] = e;
    }
    {
      float s = e;
#pragma unroll
      for (int mm = 32; mm; mm >>= 1) s += __shfl_xor(s, mm, 64);
      if (lane == 0) sRedS[wv] = s;
    }
    __syncthreads();  // (4) sums + sScores ready
    const float invS = 1.f / (sRedS[0] + sRedS[1] + sRedS[2] + sRedS[3] +
                              sRedS[4] + sRedS[5] + sRedS[6] + sRedS[7]);

    // pooling
    {
      const int ecol = tid & 63, sg = tid >> 6;
      float a = 0.f;
#pragma unroll 5
      for (int k = 0; k < 25; ++k) {
        const int s = sg + k * 8;
        a = fmaf(sScores[s], b2f(sBehB[swzB(s, ecol)]), a);
      }
      sPool[sg * 64 + ecol] = a;
    }
    __syncthreads();  // (5) sPool ready; sBehB free for next b

    if (tid < 64) {
      float a = 0.f;
#pragma unroll
      for (int sg = 0; sg < 8; ++sg) a += sPool[sg * 64 + tid];
      comb[(size_t)b * 256 + 128 + tid] = a * invS;
    }
    // next iteration's barriers protect sPool/sBehB reuse
  }
}

// ================= k2: FC head =================
__global__ __launch_bounds__(256, 2)
void din_fc(const float* __restrict__ fb1, const float* __restrict__ fw2,
            const float* __restrict__ fb2, const char* __restrict__ ws,
            float* __restrict__ out)
{
  __shared__ unsigned short sW[32768];   // fw1T swizzled image, 64 KB
  __shared__ unsigned short sA[16 * 256];// comb bf16 swizzled, 8 KB
  __shared__ float sO[64];

  const float* comb = (const float*)(ws + WS_COMB);
  const int tid  = threadIdx.x;
  const int lane = tid & 63;
  const int wv   = tid >> 6;
  const int bb   = blockIdx.x * 16;

  // stage fw1T (pre-swizzled) via global_load_lds: 64 KB = 16 iters
  {
    const char* src = ws + WS_FW1T;
    char* dst = (char*)sW;
#pragma unroll
    for (int it = 0; it < 16; ++it)
      async_g2l_16(src + it * 4096 + tid * 16, dst + it * 4096 + tid * 16);
  }
  // stage comb rows -> bf16 swizzled [16][256]
  {
    const int row = tid >> 4, d0 = (tid & 15) * 16;
    const float* src = comb + (size_t)(bb + row) * 256 + d0;
    ushort4 p0, p1, p2, p3;
    float4 v0 = *(const float4*)(src);
    float4 v1 = *(const float4*)(src + 4);
    float4 v2 = *(const float4*)(src + 8);
    float4 v3 = *(const float4*)(src + 12);
    p0.x = f2b(v0.x); p0.y = f2b(v0.y); p0.z = f2b(v0.z); p0.w = f2b(v0.w);
    p1.x = f2b(v1.x); p1.y = f2b(v1.y); p1.z = f2b(v1.z); p1.w = f2b(v1.w);
    p2.x = f2b(v2.x); p2.y = f2b(v2.y); p2.z = f2b(v2.z); p2.w = f2b(v2.w);
    p3.x = f2b(v3.x); p3.y = f2b(v3.y); p3.z = f2b(v3.z); p3.w = f2b(v3.w);
    *(ushort4*)&sA[swzW(row, d0)]     = p0;
    *(ushort4*)&sA[swzW(row, d0 + 4)] = p1;
    *(ushort4*)&sA[swzW(row, d0 + 8)]  = p2;
    *(ushort4*)&sA[swzW(row, d0 + 12)] = p3;
  }
  __syncthreads();

  const int hl = lane & 15, rq = lane >> 4;
  const int h0 = wv * 32 + hl, h1 = h0 + 16;
  f32x4 acc0 = {0.f, 0.f, 0.f, 0.f};
  f32x4 acc1 = {0.f, 0.f, 0.f, 0.f};
#pragma unroll
  for (int kk = 0; kk < 8; ++kk) {
    const short8 av = *(const short8*)&sA[swzW(hl, kk * 32 + rq * 8)];
    const short8 b0 = *(const short8*)&sW[swzW(h0, kk * 32 + rq * 8)];
    const short8 b1 = *(const short8*)&sW[swzW(h1, kk * 32 + rq * 8)];
    acc0 = __builtin_amdgcn_mfma_f32_16x16x32_bf16(av, b0, acc0, 0, 0, 0);
    acc1 = __builtin_amdgcn_mfma_f32_16x16x32_bf16(av, b1, acc1, 0, 0, 0);
  }
  const float fb10 = fb1[h0], fb11 = fb1[h1];
  const float fw20 = fw2[h0], fw21 = fw2[h1];
#pragma unroll
  for (int r = 0; r < 4; ++r) {
    float v = fmaxf(acc0[r] + fb10, 0.f) * fw20
            + fmaxf(acc1[r] + fb11, 0.f) * fw21;
    v += __shfl_xor(v, 1, 64);
    v += __shfl_xor(v, 2, 64);
    v += __shfl_xor(v, 4, 64);
    v += __shfl_xor(v, 8, 64);
    if (hl == 0) sO[wv * 16 + rq * 4 + r] = v;
  }
  __syncthreads();
  if (tid < 16)
    out[bb + tid] = sO[tid] + sO[16 + tid] + sO[32 + tid] + sO[48 + tid] + fb2[0];
}

extern "C" void kernel_launch(void* const* d_in, const int* in_sizes, int n_in,
                              void* d_out, int out_size, void* d_ws, size_t ws_size,
                              hipStream_t stream) {
  const int*   uf   = (const int*)d_in[0];
  const int*   tif  = (const int*)d_in[1];
  const int*   bseq = (const int*)d_in[2];
  const float* e0   = (const float*)d_in[3];
  const float* e1   = (const float*)d_in[4];
  const float* ei   = (const float*)d_in[5];
  const float* aw1  = (const float*)d_in[6];
  const float* ab1  = (const float*)d_in[7];
  const float* aw2  = (const float*)d_in[8];
  // d_in[9] = ab2 (unused: softmax shift-invariant)
  const float* fw1  = (const float*)d_in[10];
  const float* fb1  = (const float*)d_in[11];
  const float* fw2  = (const float*)d_in[12];
  const float* fb2  = (const float*)d_in[13];
  float* o = (float*)d_out;
  char* ws = (char*)d_ws;

  din_prep<<<dim3(192), dim3(256), 0, stream>>>(aw1, fw1, ws);
  din_main<<<dim3(512), dim3(512), 0, stream>>>(uf, tif, bseq, e0, e1, ei,
                                                ab1, aw2, ws);
  din_fc<<<dim3(256), dim3(256), 0, stream>>>(fb1, fw2, fb2, ws, o);
}